// Round 10
// baseline (3263.279 us; speedup 1.0000x reference)
//
#include <hip/hip_runtime.h>
#include <math.h>

#define S_TOT 2048
#define B_    64
#define E_    256
#define H_    256

typedef __fp16 half2v __attribute__((ext_vector_type(2)));
typedef __fp16 half8v __attribute__((ext_vector_type(8)));
typedef float  f32x4  __attribute__((ext_vector_type(4)));

__device__ __forceinline__ float dpp_xor1(float x) {
    int i = __builtin_bit_cast(int, x);
    i = __builtin_amdgcn_mov_dpp(i, 0xB1, 0xF, 0xF, true);   // quad_perm [1,0,3,2]
    return __builtin_bit_cast(float, i);
}
__device__ __forceinline__ int dpp_xor2_i(int i) {
    return __builtin_amdgcn_mov_dpp(i, 0x4E, 0xF, 0xF, true); // quad_perm [2,3,0,1]
}

// Fused kernel. Scan restructured to MFMA (R10): MfmaUtil was 0.0 on a
// matmul-shaped op; the fdot2 structure's per-step cost (issue+reduce+tanh+
// LDS round trip per SINGLE batch) saturated at ~1300 cyc/step across every
// micro-lever (R1-R9). New scan: 4 blocks x 16 batches, 4 waves each; wave wv
// owns cols [wv*64, wv*64+64). Per step/wave: 8 ds_read_b128 A-frags +
// 32 mfma_f32_16x16x32_f16 + 16 tanh + packed b64 writes + 1 barrier.
// Whh B-frags resident in 128 regs (unified VGPR/AGPR file: MFMA reads AGPRs
// natively, so allocator parking is free — unlike fdot2).
// H in LDS: [2][16][256] f16, swizzled byte ^= (m&7)<<4 (stride-512B rows
// would otherwise be a 16-way conflict on fragment reads).
// k-slot placement of A/B frags is self-consistent (dot is k-permutation-
// invariant); C/D layout col=lane&15,row=(lane>>4)*4+reg is m89-verified.
__global__ __launch_bounds__(256)
__attribute__((amdgpu_waves_per_eu(1, 1)))
void fused_step(
    const float* __restrict__ A,       // sentence chunk for gemm [Mc, E] (or null)
    const float* __restrict__ Wih,     // [E, H]
    const float* __restrict__ bias,    // [H]
    float*       __restrict__ xp_next, // [chunk*B, H] gemm output
    const float* __restrict__ xp_cur,  // [steps, B, H] scan input
    const float* __restrict__ Whh,     // [H, H]
    float*       __restrict__ h,       // [B, H] persistent state (= d_out)
    int steps, int scan_blocks)
{
    __shared__ float smem[32 * 68 + 32 * 64];   // gemm tiles; scan uses front 16KB
    const int tid = threadIdx.x;

    if ((int)blockIdx.x < scan_blocks) {
        // ---------------- MFMA scan: 16 batches per block ----------------
        char* hb = (char*)smem;              // [2][16][256] f16, swizzled
        const int b0   = blockIdx.x * 16;
        const int lane = tid & 63;
        const int wv   = tid >> 6;           // wave id 0..3
        const int lm   = lane & 15;          // A row / C col within 16-tile
        const int lg   = lane >> 4;          // k-group / C row-group
        const int coln = wv * 64 + lm;       // output col base (+jt*16)
        const int row0 = lg * 4;             // output row base (+r)

        // ---- B-fragments: wf_kt_jt, 32 x half8v = 128 regs, loaded once ----
#define DECLWF(kt,jt) half8v wf_##kt##_##jt;
#define WF_ALL(X) \
        X(0,0) X(0,1) X(0,2) X(0,3)  X(1,0) X(1,1) X(1,2) X(1,3) \
        X(2,0) X(2,1) X(2,2) X(2,3)  X(3,0) X(3,1) X(3,2) X(3,3) \
        X(4,0) X(4,1) X(4,2) X(4,3)  X(5,0) X(5,1) X(5,2) X(5,3) \
        X(6,0) X(6,1) X(6,2) X(6,3)  X(7,0) X(7,1) X(7,2) X(7,3)
        WF_ALL(DECLWF)

#define LOADWF(kt,jt) { \
        const float* p_ = &Whh[(size_t)((kt)*32 + lg*8) * H_ + wv*64 + (jt)*16 + lm]; \
        int i0_ = __builtin_bit_cast(int, __builtin_amdgcn_cvt_pkrtz(p_[0],     p_[H_])); \
        int i1_ = __builtin_bit_cast(int, __builtin_amdgcn_cvt_pkrtz(p_[2*H_],  p_[3*H_])); \
        int i2_ = __builtin_bit_cast(int, __builtin_amdgcn_cvt_pkrtz(p_[4*H_],  p_[5*H_])); \
        int i3_ = __builtin_bit_cast(int, __builtin_amdgcn_cvt_pkrtz(p_[6*H_],  p_[7*H_])); \
        asm volatile("" : "+v"(i0_), "+v"(i1_), "+v"(i2_), "+v"(i3_)); \
        int4 t_; t_.x = i0_; t_.y = i1_; t_.z = i2_; t_.w = i3_; \
        wf_##kt##_##jt = __builtin_bit_cast(half8v, t_); \
    }
        WF_ALL(LOADWF)

        // ---- init: stage h[b0..b0+16) into LDS buf 0 (swizzled) ----
        {
            const int m  = tid >> 4;
            const int kq = (tid & 15) * 16;
            const float* src = &h[(size_t)(b0 + m) * H_ + kq];
            float4 f0 = *(const float4*)(src + 0);
            float4 f1 = *(const float4*)(src + 4);
            float4 f2 = *(const float4*)(src + 8);
            float4 f3 = *(const float4*)(src + 12);
            int4 u0, u1;
            u0.x = __builtin_bit_cast(int, __builtin_amdgcn_cvt_pkrtz(f0.x, f0.y));
            u0.y = __builtin_bit_cast(int, __builtin_amdgcn_cvt_pkrtz(f0.z, f0.w));
            u0.z = __builtin_bit_cast(int, __builtin_amdgcn_cvt_pkrtz(f1.x, f1.y));
            u0.w = __builtin_bit_cast(int, __builtin_amdgcn_cvt_pkrtz(f1.z, f1.w));
            u1.x = __builtin_bit_cast(int, __builtin_amdgcn_cvt_pkrtz(f2.x, f2.y));
            u1.y = __builtin_bit_cast(int, __builtin_amdgcn_cvt_pkrtz(f2.z, f2.w));
            u1.z = __builtin_bit_cast(int, __builtin_amdgcn_cvt_pkrtz(f3.x, f3.y));
            u1.w = __builtin_bit_cast(int, __builtin_amdgcn_cvt_pkrtz(f3.z, f3.w));
            const int base = m * 512 + kq * 2;
            *(int4*)(hb + ((base)      ^ ((m & 7) << 4))) = u0;
            *(int4*)(hb + ((base + 16) ^ ((m & 7) << 4))) = u1;
        }

        // ---- loop-invariant offsets ----
        int ro[8];                            // A-frag read offsets (bytes)
        #pragma unroll
        for (int kt = 0; kt < 8; kt++)
            ro[kt] = (lm * 512 + kt * 64 + lg * 16) ^ ((lm & 7) << 4);
        int wo[16];                           // packed-write offsets (bytes)
        #pragma unroll
        for (int jt = 0; jt < 4; jt++)
            #pragma unroll
            for (int r = 0; r < 4; r++) {
                const int m = row0 + r, n = coln + jt * 16;
                wo[jt * 4 + r] = (m * 512 + n * 2) ^ ((m & 7) << 4);
            }
        const size_t xcol = (size_t)(b0 + row0) * H_ + coln;   // xp/h base

        // xp prefetch for step 0
        float xc[16];
        #pragma unroll
        for (int jt = 0; jt < 4; jt++)
            #pragma unroll
            for (int r = 0; r < 4; r++)
                xc[jt * 4 + r] = xp_cur[xcol + (size_t)r * H_ + jt * 16];

        __syncthreads();

        int p = 0;
        for (int s = 0; s < steps; s++) {
            const char* rb = hb + p * 8192;
            char*       wb = hb + (p ^ 1) * 8192;

            // A-fragments: 8 x ds_read_b128
#define LOADAF(kt) half8v af##kt = __builtin_bit_cast(half8v, *(const float4*)(rb + ro[kt]));
            LOADAF(0) LOADAF(1) LOADAF(2) LOADAF(3)
            LOADAF(4) LOADAF(5) LOADAF(6) LOADAF(7)

            // xp prefetch for s+1 (overlaps MFMA)
            float xn[16];
            if (s + 1 < steps) {
                const size_t xb = (size_t)(s + 1) * B_ * H_ + xcol;
                #pragma unroll
                for (int jt = 0; jt < 4; jt++)
                    #pragma unroll
                    for (int r = 0; r < 4; r++)
                        xn[jt * 4 + r] = xp_cur[xb + (size_t)r * H_ + jt * 16];
            }

            // 32 MFMA: 4 j-tiles x 8 k-steps
            f32x4 c0 = {0.f,0.f,0.f,0.f}, c1 = {0.f,0.f,0.f,0.f};
            f32x4 c2 = {0.f,0.f,0.f,0.f}, c3 = {0.f,0.f,0.f,0.f};
#define MFJT(jt) \
            c##jt = __builtin_amdgcn_mfma_f32_16x16x32_f16(af0, wf_0_##jt, c##jt, 0,0,0); \
            c##jt = __builtin_amdgcn_mfma_f32_16x16x32_f16(af1, wf_1_##jt, c##jt, 0,0,0); \
            c##jt = __builtin_amdgcn_mfma_f32_16x16x32_f16(af2, wf_2_##jt, c##jt, 0,0,0); \
            c##jt = __builtin_amdgcn_mfma_f32_16x16x32_f16(af3, wf_3_##jt, c##jt, 0,0,0); \
            c##jt = __builtin_amdgcn_mfma_f32_16x16x32_f16(af4, wf_4_##jt, c##jt, 0,0,0); \
            c##jt = __builtin_amdgcn_mfma_f32_16x16x32_f16(af5, wf_5_##jt, c##jt, 0,0,0); \
            c##jt = __builtin_amdgcn_mfma_f32_16x16x32_f16(af6, wf_6_##jt, c##jt, 0,0,0); \
            c##jt = __builtin_amdgcn_mfma_f32_16x16x32_f16(af7, wf_7_##jt, c##jt, 0,0,0);
            MFJT(0) MFJT(1) MFJT(2) MFJT(3)

            // add xp, tanh; optional fp32 carry-out on last step
            float hv[16];
#define FIN(jt, r) { \
            float v_  = c##jt[r] + xc[(jt)*4 + (r)]; \
            float e2_ = __expf(2.f * v_); \
            hv[(jt)*4 + (r)] = 1.f - 2.f / (e2_ + 1.f); \
        }
            FIN(0,0) FIN(0,1) FIN(0,2) FIN(0,3)
            FIN(1,0) FIN(1,1) FIN(1,2) FIN(1,3)
            FIN(2,0) FIN(2,1) FIN(2,2) FIN(2,3)
            FIN(3,0) FIN(3,1) FIN(3,2) FIN(3,3)
            if (s == steps - 1) {
                #pragma unroll
                for (int jt = 0; jt < 4; jt++)
                    #pragma unroll
                    for (int r = 0; r < 4; r++)
                        h[xcol + (size_t)r * H_ + jt * 16] = hv[jt * 4 + r];
            }

            // pack 4 consecutive cols into lane (lane&3)==0, write b64
            int pkA[16], pkB[16];
            #pragma unroll
            for (int i = 0; i < 16; i++) {
                float o1 = dpp_xor1(hv[i]);
                pkA[i] = __builtin_bit_cast(int, __builtin_amdgcn_cvt_pkrtz(hv[i], o1));
                pkB[i] = dpp_xor2_i(pkA[i]);
            }
            if ((lane & 3) == 0) {
                #pragma unroll
                for (int i = 0; i < 16; i++) {
                    int2 w2; w2.x = pkA[i]; w2.y = pkB[i];
                    *(int2*)(wb + wo[i]) = w2;
                }
            }

            #pragma unroll
            for (int i = 0; i < 16; i++) xc[i] = xn[i];

            // barrier without vmcnt drain (xp prefetch stays in flight)
            asm volatile("s_waitcnt lgkmcnt(0)" ::: "memory");
            __builtin_amdgcn_s_barrier();
            p ^= 1;
        }
    } else if (A != nullptr) {
        // ---------------- gemm: xp_next = A @ Wih + bias (256 threads) -------
        float (*As)[68] = (float(*)[68])smem;
        float (*Bs)[64] = (float(*)[64])(smem + 32 * 68);

        const int gid = blockIdx.x - scan_blocks;
        const int bm = (gid >> 2) * 64;
        const int bn = (gid & 3) * 64;
        const int tx = tid & 15;
        const int ty = tid >> 4;

        float acc[4][4] = {};

        const int ar = tid >> 3;
        const int ak = (tid & 7) << 2;
        const int br = tid >> 4;
        const int bc = (tid & 15) << 2;

        for (int k0 = 0; k0 < E_; k0 += 32) {
            float4 a0 = *(const float4*)&A[(size_t)(bm + ar)      * E_ + k0 + ak];
            float4 a1 = *(const float4*)&A[(size_t)(bm + ar + 32) * E_ + k0 + ak];
            float4 bv0 = *(const float4*)&Wih[(size_t)(k0 + br)      * H_ + bn + bc];
            float4 bv1 = *(const float4*)&Wih[(size_t)(k0 + br + 16) * H_ + bn + bc];

            As[ak+0][ar]    = a0.x; As[ak+1][ar]    = a0.y; As[ak+2][ar]    = a0.z; As[ak+3][ar]    = a0.w;
            As[ak+0][ar+32] = a1.x; As[ak+1][ar+32] = a1.y; As[ak+2][ar+32] = a1.z; As[ak+3][ar+32] = a1.w;
            *(float4*)&Bs[br][bc]      = bv0;
            *(float4*)&Bs[br + 16][bc] = bv1;
            __syncthreads();

            #pragma unroll
            for (int kk = 0; kk < 32; kk++) {
                const float4 av = *(const float4*)&As[kk][ty << 2];
                const float4 bv = *(const float4*)&Bs[kk][tx << 2];
                acc[0][0] += av.x*bv.x; acc[0][1] += av.x*bv.y; acc[0][2] += av.x*bv.z; acc[0][3] += av.x*bv.w;
                acc[1][0] += av.y*bv.x; acc[1][1] += av.y*bv.y; acc[1][2] += av.y*bv.z; acc[1][3] += av.y*bv.w;
                acc[2][0] += av.z*bv.x; acc[2][1] += av.z*bv.y; acc[2][2] += av.z*bv.z; acc[2][3] += av.z*bv.w;
                acc[3][0] += av.w*bv.x; acc[3][1] += av.w*bv.y; acc[3][2] += av.w*bv.z; acc[3][3] += av.w*bv.w;
            }
            __syncthreads();
        }

        const float4 bb = *(const float4*)&bias[bn + (tx << 2)];
        #pragma unroll
        for (int i = 0; i < 4; i++) {
            float4 o;
            o.x = acc[i][0] + bb.x;
            o.y = acc[i][1] + bb.y;
            o.z = acc[i][2] + bb.z;
            o.w = acc[i][3] + bb.w;
            *(float4*)&xp_next[(size_t)(bm + (ty << 2) + i) * H_ + bn + (tx << 2)] = o;
        }
    }
}

extern "C" void kernel_launch(void* const* d_in, const int* in_sizes, int n_in,
                              void* d_out, int out_size, void* d_ws, size_t ws_size,
                              hipStream_t stream)
{
    const float* sentence = (const float*)d_in[0];  // [S,B,E]
    const float* h0       = (const float*)d_in[1];  // [B,H]
    const float* W_ih     = (const float*)d_in[2];  // [E,H]
    const float* W_hh     = (const float*)d_in[3];  // [H,H]
    const float* bias     = (const float*)d_in[4];  // [H]
    float* h  = (float*)d_out;
    float* ws = (float*)d_ws;

    // two ping-pong xp buffers, each [chunk*B, H]
    int chunk = 256;
    while ((size_t)2 * chunk * B_ * H_ * sizeof(float) > ws_size && chunk > 32)
        chunk >>= 1;
    const int nchunk = S_TOT / chunk;
    float* buf[2] = { ws, ws + (size_t)chunk * B_ * H_ };

    (void)hipMemcpyAsync(h, h0, B_ * H_ * sizeof(float), hipMemcpyDeviceToDevice, stream);

    // pure gemm for chunk 0
    fused_step<<<chunk * 4, 256, 0, stream>>>(sentence, W_ih, bias, buf[0],
                                              nullptr, W_hh, h, 0, 0);
    for (int c = 0; c < nchunk; c++) {
        const bool last = (c == nchunk - 1);
        const int gemmb = last ? 0 : chunk * 4;
        const float* Anext = last ? nullptr
                                  : sentence + (size_t)(c + 1) * chunk * B_ * E_;
        fused_step<<<4 + gemmb, 256, 0, stream>>>(Anext, W_ih, bias,
                                                  buf[(c + 1) & 1],
                                                  buf[c & 1], W_hh, h,
                                                  chunk, 4);
    }
}